// Round 7
// baseline (1626.802 us; speedup 1.0000x reference)
//
#include <hip/hip_runtime.h>

typedef __bf16 bf16x8 __attribute__((ext_vector_type(8)));
typedef float floatx4 __attribute__((ext_vector_type(4)));

#define MFMA(a, b, c) __builtin_amdgcn_mfma_f32_16x16x32_bf16((a), (b), (c), 0, 0, 0)

__device__ __forceinline__ float bf2f(ushort u) {
    union { unsigned int i; float f; } v; v.i = ((unsigned int)u) << 16; return v.f;
}
__device__ __forceinline__ ushort f2bf(float f) {
    union { float f; unsigned int i; } v; v.f = f;
    unsigned int r = v.i + 0x7fffu + ((v.i >> 16) & 1u);
    return (ushort)(r >> 16);
}
__device__ __forceinline__ bf16x8 ldb8(const ushort* p) { return *(const bf16x8*)p; }

// ---------------------------------------------------------------- fp32 -> bf16 transpose
__global__ __launch_bounds__(256) void transpose_f32_bf16(
    const float* __restrict__ in, ushort* __restrict__ out, int R, int C) {
    __shared__ ushort tile[32][33];
    const int c0 = blockIdx.x * 32, r0 = blockIdx.y * 32;
    const int tx = threadIdx.x, ty = threadIdx.y;
    #pragma unroll
    for (int i = 0; i < 32; i += 8) {
        int r = r0 + ty + i, c = c0 + tx;
        if (r < R && c < C) tile[ty + i][tx] = f2bf(in[(long)r * C + c]);
    }
    __syncthreads();
    #pragma unroll
    for (int i = 0; i < 32; i += 8) {
        int r = c0 + ty + i, c = r0 + tx;   // out is C x R
        if (r < C && c < R) out[(long)r * R + c] = tile[tx][ty + i];
    }
}

// ---------------------------------------------------------------- fp32 -> bf16 elementwise (n % 4 == 0)
__global__ __launch_bounds__(256) void cvt_f32_bf16(
    const float* __restrict__ in, ushort* __restrict__ out, long n) {
    const long i = ((long)blockIdx.x * 256 + threadIdx.x) * 4;
    if (i >= n) return;
    float4 v = *(const float4*)(in + i);
    ushort4 o;
    o.x = f2bf(v.x); o.y = f2bf(v.y); o.z = f2bf(v.z); o.w = f2bf(v.w);
    *(ushort4*)(out + i) = o;
}

// ---------------------------------------------------------------- GEMM 64-tile (for N=576 case)
__global__ __launch_bounds__(256, 2) void gemm_bt(
    const ushort* __restrict__ A, const ushort* __restrict__ Bt,
    void* __restrict__ C, int K, int lda, int ldb, int ldc,
    long aZ, long bZ, long cZ, int c_f32) {
    __shared__ __align__(16) ushort As[64][72];
    __shared__ __align__(16) ushort Bs[64][72];
    const int z = blockIdx.z;
    const ushort* Ab = A + (long)z * aZ;
    const ushort* Bb = Bt + (long)z * bZ;
    const long m0 = (long)blockIdx.y * 64;
    const long n0 = (long)blockIdx.x * 64;
    const int tid = threadIdx.x;
    const int lane = tid & 63, w = tid >> 6;
    const int wm = (w >> 1) * 32, wn = (w & 1) * 32;
    const int lrow = lane & 15, quad = lane >> 4;

    floatx4 acc[2][2] = {};

    const int r0_ = tid >> 3, c0_ = (tid & 7) * 8;
    const int r1_ = r0_ + 32, c1_ = c0_;

    for (int k0 = 0; k0 < K; k0 += 64) {
        uint4 a0 = *(const uint4*)(Ab + (m0 + r0_) * lda + k0 + c0_);
        uint4 a1 = *(const uint4*)(Ab + (m0 + r1_) * lda + k0 + c1_);
        uint4 b0 = *(const uint4*)(Bb + (n0 + r0_) * ldb + k0 + c0_);
        uint4 b1 = *(const uint4*)(Bb + (n0 + r1_) * ldb + k0 + c1_);
        __syncthreads();
        *(uint4*)&As[r0_][c0_] = a0;
        *(uint4*)&As[r1_][c1_] = a1;
        *(uint4*)&Bs[r0_][c0_] = b0;
        *(uint4*)&Bs[r1_][c1_] = b1;
        __syncthreads();
        #pragma unroll
        for (int kk = 0; kk < 64; kk += 32) {
            bf16x8 af0 = ldb8(&As[wm + lrow][kk + quad * 8]);
            bf16x8 af1 = ldb8(&As[wm + 16 + lrow][kk + quad * 8]);
            bf16x8 bf0 = ldb8(&Bs[wn + lrow][kk + quad * 8]);
            bf16x8 bf1 = ldb8(&Bs[wn + 16 + lrow][kk + quad * 8]);
            acc[0][0] = MFMA(af0, bf0, acc[0][0]);
            acc[0][1] = MFMA(af0, bf1, acc[0][1]);
            acc[1][0] = MFMA(af1, bf0, acc[1][0]);
            acc[1][1] = MFMA(af1, bf1, acc[1][1]);
        }
    }
    if (c_f32) {
        float* Cb = (float*)C + (long)z * cZ;
        #pragma unroll
        for (int mt = 0; mt < 2; ++mt)
            #pragma unroll
            for (int nt = 0; nt < 2; ++nt)
                #pragma unroll
                for (int r = 0; r < 4; ++r)
                    Cb[(m0 + wm + mt * 16 + quad * 4 + r) * ldc + n0 + wn + nt * 16 + lrow] = acc[mt][nt][r];
    } else {
        ushort* Cb = (ushort*)C + (long)z * cZ;
        #pragma unroll
        for (int mt = 0; mt < 2; ++mt)
            #pragma unroll
            for (int nt = 0; nt < 2; ++nt)
                #pragma unroll
                for (int r = 0; r < 4; ++r)
                    Cb[(m0 + wm + mt * 16 + quad * 4 + r) * ldc + n0 + wn + nt * 16 + lrow] = f2bf(acc[mt][nt][r]);
    }
}

// ---------------------------------------------------------------- GEMM 128-tile, global_load_lds (m97-class)
__global__ __launch_bounds__(256, 2) void gemm_bt128(
    const ushort* __restrict__ A, const ushort* __restrict__ Bt,
    void* __restrict__ C, int K, int lda, int ldb, int ldc,
    long aZ, long bZ, long cZ, int c_f32) {
    __shared__ __align__(16) ushort As[128 * 64];
    __shared__ __align__(16) ushort Bs[128 * 64];
    const int z = blockIdx.z;
    const ushort* Ab = A + (long)z * aZ;
    const ushort* Bb = Bt + (long)z * bZ;
    const long m0 = (long)blockIdx.y * 128;
    const long n0 = (long)blockIdx.x * 128;
    const int tid = threadIdx.x;
    const int lane = tid & 63, w = tid >> 6;
    const int wm = (w >> 1) * 64, wn = (w & 1) * 64;
    const int lrow = lane & 15, quad = lane >> 4;

    floatx4 acc[4][4] = {};

    for (int k0 = 0; k0 < K; k0 += 64) {
        __syncthreads();  // prev-iter LDS reads done before overwrite
        #pragma unroll
        for (int t = 0; t < 4; ++t) {
            const int c = t * 256 + tid;          // chunk id: lds dest = base + lane*16
            const int r = c >> 3, kc = (c & 7) * 8;
            __builtin_amdgcn_global_load_lds(
                (const __attribute__((address_space(1))) unsigned int*)(Ab + (m0 + r) * lda + k0 + kc),
                (__attribute__((address_space(3))) unsigned int*)(As + (long)c * 8), 16, 0, 0);
            __builtin_amdgcn_global_load_lds(
                (const __attribute__((address_space(1))) unsigned int*)(Bb + (n0 + r) * ldb + k0 + kc),
                (__attribute__((address_space(3))) unsigned int*)(Bs + (long)c * 8), 16, 0, 0);
        }
        __syncthreads();  // drains vmcnt -> staged tile visible
        #pragma unroll
        for (int kk = 0; kk < 64; kk += 32) {
            bf16x8 af[4], bv[4];
            #pragma unroll
            for (int i = 0; i < 4; ++i) {
                af[i] = ldb8(&As[(wm + i * 16 + lrow) * 64 + kk + quad * 8]);
                bv[i] = ldb8(&Bs[(wn + i * 16 + lrow) * 64 + kk + quad * 8]);
            }
            #pragma unroll
            for (int i = 0; i < 4; ++i)
                #pragma unroll
                for (int j = 0; j < 4; ++j)
                    acc[i][j] = MFMA(af[i], bv[j], acc[i][j]);
        }
    }
    if (c_f32) {
        float* Cb = (float*)C + (long)z * cZ;
        #pragma unroll
        for (int mt = 0; mt < 4; ++mt)
            #pragma unroll
            for (int nt = 0; nt < 4; ++nt)
                #pragma unroll
                for (int r = 0; r < 4; ++r)
                    Cb[(m0 + wm + mt * 16 + quad * 4 + r) * ldc + n0 + wn + nt * 16 + lrow] = acc[mt][nt][r];
    } else {
        ushort* Cb = (ushort*)C + (long)z * cZ;
        #pragma unroll
        for (int mt = 0; mt < 4; ++mt)
            #pragma unroll
            for (int nt = 0; nt < 4; ++nt)
                #pragma unroll
                for (int r = 0; r < 4; ++r)
                    Cb[(m0 + wm + mt * 16 + quad * 4 + r) * ldc + n0 + wn + nt * 16 + lrow] = f2bf(acc[mt][nt][r]);
    }
}

// ---------------------------------------------------------------- RMSNorm D=1536 (supports in==out; w is fp32)
__global__ __launch_bounds__(256) void rms1536(
    const ushort* in, const float* __restrict__ w, ushort* out) {
    const int row = blockIdx.x, t = threadIdx.x;
    const ushort* ip = in + (long)row * 1536;
    float v[6]; float ss = 0.f;
    #pragma unroll
    for (int i = 0; i < 6; ++i) { v[i] = bf2f(ip[i * 256 + t]); ss += v[i] * v[i]; }
    __shared__ float red[256];
    red[t] = ss; __syncthreads();
    for (int st = 128; st > 0; st >>= 1) { if (t < st) red[t] += red[t + st]; __syncthreads(); }
    const float sc = rsqrtf(red[0] * (1.f / 1536.f) + 1e-6f);
    ushort* op = out + (long)row * 1536;
    #pragma unroll
    for (int i = 0; i < 6; ++i) op[i * 256 + t] = f2bf(v[i] * sc * w[i * 256 + t]);
}

// ---------------------------------------------------------------- q RoPE
__global__ __launch_bounds__(256) void qrope(
    const ushort* __restrict__ q, const float* __restrict__ freqs,
    ushort* __restrict__ qpe) {
    const int tok = blockIdx.x;
    const int s = tok & 2047;
    const int t = threadIdx.x;
    #pragma unroll
    for (int p = 0; p < 2; ++p) {
        const int idx = p * 256 + t;
        const int h = idx >> 5, i = idx & 31;
        const long base = (long)tok * 3072 + h * 192 + 128 + 2 * i;
        float x0 = bf2f(q[base]), x1 = bf2f(q[base + 1]);
        float th = freqs[s * 32 + i];
        float sn = sinf(th), cs = cosf(th);
        const long ob = (long)tok * 1024 + h * 64 + 2 * i;
        qpe[ob]     = f2bf(x0 * cs - x1 * sn);
        qpe[ob + 1] = f2bf(x0 * sn + x1 * cs);
    }
}

// ---------------------------------------------------------------- kv prep
__global__ __launch_bounds__(256) void kvprep(
    const ushort* __restrict__ kv, const float* __restrict__ w,
    const float* __restrict__ freqs, ushort* __restrict__ kvc,
    ushort* __restrict__ kvcT, ushort* __restrict__ kpe) {
    const int tok = blockIdx.x;
    const int b = tok >> 11, s = tok & 2047;
    const int t = threadIdx.x;
    const float v0 = bf2f(kv[(long)tok * 576 + t]);
    const float v1 = bf2f(kv[(long)tok * 576 + 256 + t]);
    __shared__ float red[256];
    red[t] = v0 * v0 + v1 * v1; __syncthreads();
    for (int st = 128; st > 0; st >>= 1) { if (t < st) red[t] += red[t + st]; __syncthreads(); }
    const float sc = rsqrtf(red[0] * (1.f / 512.f) + 1e-6f);
    const float y0 = v0 * sc * w[t];
    const float y1 = v1 * sc * w[256 + t];
    kvc[(long)tok * 512 + t] = f2bf(y0);
    kvc[(long)tok * 512 + 256 + t] = f2bf(y1);
    kvcT[(long)b * 1048576 + (long)t * 2048 + s] = f2bf(y0);
    kvcT[(long)b * 1048576 + (long)(256 + t) * 2048 + s] = f2bf(y1);
    if (t < 32) {
        float x0 = bf2f(kv[(long)tok * 576 + 512 + 2 * t]);
        float x1 = bf2f(kv[(long)tok * 576 + 512 + 2 * t + 1]);
        float th = freqs[s * 32 + t];
        float sn = sinf(th), cs = cosf(th);
        kpe[(long)tok * 64 + 2 * t]     = f2bf(x0 * cs - x1 * sn);
        kpe[(long)tok * 64 + 2 * t + 1] = f2bf(x0 * sn + x1 * cs);
    }
}

// ---------------------------------------------------------------- flash attention v4
// Grid (16,16,2): block handles q-tiles {qx, 31-qx} -> uniform 34 kv-iters of SIZE 64.
// v4 deltas vs v3: (a) kv-tile 32->64 (halves iterations: barriers, shuffle chains,
// staging-latency exposures); (b) K staged via global_load_lds DMA into an UNPADDED
// XOR-swizzled Ks[64][512] (chunk' = chunk ^ (row&7); QK reads land 2-way = free);
// no VGPR round-trip, no ds_writes; pre-barrier vmcnt(0) drain covers the DMA.
__global__ __launch_bounds__(256, 2) void mla_attn4(
    ushort* __restrict__ qo,           // in: q_abs (4096,16,512); out: O (same)
    const ushort* __restrict__ q_pe,   // (4096,16,64)
    const ushort* __restrict__ kvc,    // (4096,512)
    const ushort* __restrict__ kvcT,   // (2,512,2048)
    const ushort* __restrict__ kpe) {  // (4096,64)
    __shared__ __align__(16) ushort Ks[64 * 512];  // swizzled, unpadded (64 KB)
    __shared__ __align__(16) ushort P[64][72];     // cols 64-65: alpha(f32), 66-67: l(f32)
    const int qx = blockIdx.x, h = blockIdx.y, b = blockIdx.z;
    const int tid = threadIdx.x, lane = tid & 63, w = tid >> 6;
    const int lrow = lane & 15, quad = lane >> 4;
    const long bb = (long)b * 2048;
    const float scale = 0.07216878364870323f;  // 192^-0.5
    const int sw = lrow & 7;                   // read-side swizzle key

    for (int half = 0; half < 2; ++half) {
        const int qt = half ? (31 - qx) : qx;
        const int qrow = qt * 64;
        const long tokb = bb + qrow;

        bf16x8 qa[18];
        {
            const ushort* qp_ = qo + (tokb + w * 16 + lrow) * 8192 + h * 512 + quad * 8;
            #pragma unroll
            for (int ks = 0; ks < 16; ++ks) qa[ks] = ldb8(qp_ + ks * 32);
            const ushort* qq = q_pe + (tokb + w * 16 + lrow) * 1024 + h * 64 + quad * 8;
            qa[16] = ldb8(qq); qa[17] = ldb8(qq + 32);
        }

        floatx4 oacc[4][8] = {};        // [m-frag][v-frag]
        float m_i[4], l_i[4];
        #pragma unroll
        for (int r = 0; r < 4; ++r) { m_i[r] = -1e30f; l_i[r] = 0.f; }

        const int niter = qt + 1;
        for (int t = 0; t < niter; ++t) {
            const int kv0 = t * 64;
            // ---- stage K-tile (64 x 512) via DMA, swizzled ----
            // chunk q = i*256+tid; row = q>>6 (uniform per wave-instr); pos = q&63;
            // logical chunk lc = pos ^ (row&7); LDS dest = Ks + q*8 (lane-contiguous).
            #pragma unroll
            for (int i = 0; i < 16; ++i) {
                const int cq = i * 256 + tid;
                const int row = cq >> 6, pos = cq & 63;
                const int lc = pos ^ (row & 7);
                __builtin_amdgcn_global_load_lds(
                    (const __attribute__((address_space(1))) unsigned int*)(kvc + (bb + kv0 + row) * 512 + lc * 8),
                    (__attribute__((address_space(3))) unsigned int*)(Ks + (long)cq * 8), 16, 0, 0);
            }
            __syncthreads();  // A: DMA drained (vmcnt 0) + prev PV done (P safe)

            // ---- QK^T: rows w*16..+16  x  kv-cols 0..63 ----
            floatx4 sacc[4] = {};
            bf16x8 kp[4][2];
            #pragma unroll
            for (int nt = 0; nt < 4; ++nt) {
                const ushort* pb = kpe + (bb + kv0 + nt * 16 + lrow) * 64 + quad * 8;
                kp[nt][0] = ldb8(pb); kp[nt][1] = ldb8(pb + 32);
            }
            #pragma unroll
            for (int ks = 0; ks < 16; ++ks) {
                #pragma unroll
                for (int nt = 0; nt < 4; ++nt) {
                    const int row = nt * 16 + lrow;
                    const int lch = (ks * 4 + quad) ^ sw;
                    bf16x8 bfr = ldb8(&Ks[row * 512 + lch * 8]);
                    sacc[nt] = MFMA(qa[ks], bfr, sacc[nt]);
                }
            }
            #pragma unroll
            for (int nt = 0; nt < 4; ++nt) {
                sacc[nt] = MFMA(qa[16], kp[nt][0], sacc[nt]);
                sacc[nt] = MFMA(qa[17], kp[nt][1], sacc[nt]);
            }

            // ---- prefetch V b-frags (v-slice w*128..+128, kv 0..63) ----
            bf16x8 vf[8][2];
            {
                const ushort* vb = kvcT + (long)b * 1048576 + (long)(w * 128 + lrow) * 2048 + kv0 + quad * 8;
                #pragma unroll
                for (int nf = 0; nf < 8; ++nf) {
                    vf[nf][0] = ldb8(vb + (long)nf * 16 * 2048);
                    vf[nf][1] = ldb8(vb + (long)nf * 16 * 2048 + 32);
                }
            }

            // ---- online softmax (rows w*16 + quad*4 + r) ----
            #pragma unroll
            for (int r = 0; r < 4; ++r) {
                const int rloc = w * 16 + quad * 4 + r;
                const int row_s = qrow + rloc;
                float pv[4]; float smax = -1e30f;
                #pragma unroll
                for (int nt = 0; nt < 4; ++nt) {
                    float sv = sacc[nt][r] * scale;
                    if (kv0 + nt * 16 + lrow > row_s) sv = -1e30f;
                    pv[nt] = sv;
                    smax = fmaxf(smax, sv);
                }
                #pragma unroll
                for (int off = 1; off < 16; off <<= 1)
                    smax = fmaxf(smax, __shfl_xor(smax, off));
                const float mnew = fmaxf(m_i[r], smax);
                const float alpha = __expf(m_i[r] - mnew);
                float ps = 0.f;
                #pragma unroll
                for (int nt = 0; nt < 4; ++nt) {
                    float p = __expf(pv[nt] - mnew);
                    ps += p;
                    P[rloc][nt * 16 + lrow] = f2bf(p);
                }
                #pragma unroll
                for (int off = 1; off < 16; off <<= 1)
                    ps += __shfl_xor(ps, off);
                l_i[r] = l_i[r] * alpha + ps;
                m_i[r] = mnew;
                if (lrow == 0) *(float*)&P[rloc][64] = alpha;
            }
            __syncthreads();  // B: P + alpha visible

            // ---- PV: wave w owns v-slice [w*128,+128), all 64 q-rows, kv 0..63 ----
            #pragma unroll
            for (int mf = 0; mf < 4; ++mf) {
                float al[4];
                #pragma unroll
                for (int r = 0; r < 4; ++r) al[r] = *(const float*)&P[mf * 16 + quad * 4 + r][64];
                const int need = (al[0] != 1.f) | (al[1] != 1.f) | (al[2] != 1.f) | (al[3] != 1.f);
                if (__any(need)) {
                    #pragma unroll
                    for (int nf = 0; nf < 8; ++nf)
                        #pragma unroll
                        for (int r = 0; r < 4; ++r) oacc[mf][nf][r] *= al[r];
                }
                bf16x8 pf0 = ldb8(&P[mf * 16 + lrow][quad * 8]);
                bf16x8 pf1 = ldb8(&P[mf * 16 + lrow][32 + quad * 8]);
                #pragma unroll
                for (int nf = 0; nf < 8; ++nf) {
                    oacc[mf][nf] = MFMA(pf0, vf[nf][0], oacc[mf][nf]);
                    oacc[mf][nf] = MFMA(pf1, vf[nf][1], oacc[mf][nf]);
                }
            }
        }

        // ---- epilogue: publish l, divide, store O in place ----
        {
            #pragma unroll
            for (int r = 0; r < 4; ++r)
                if (lrow == 0) *(float*)&P[w * 16 + quad * 4 + r][66] = l_i[r];
        }
        __syncthreads();
        #pragma unroll
        for (int mf = 0; mf < 4; ++mf) {
            float li[4];
            #pragma unroll
            for (int r = 0; r < 4; ++r) li[r] = *(const float*)&P[mf * 16 + quad * 4 + r][66];
            #pragma unroll
            for (int nf = 0; nf < 8; ++nf)
                #pragma unroll
                for (int r = 0; r < 4; ++r) {
                    long tok = tokb + mf * 16 + quad * 4 + r;
                    qo[tok * 8192 + h * 512 + w * 128 + nf * 16 + lrow] = f2bf(oacc[mf][nf][r] / li[r]);
                }
        }
        __syncthreads();  // protect P/Ks before next half
    }
}

// ---------------------------------------------------------------- launcher
extern "C" void kernel_launch(void* const* d_in, const int* in_sizes, int n_in,
                              void* d_out, int out_size, void* d_ws, size_t ws_size,
                              hipStream_t stream) {
    const float* x      = (const float*)d_in[0];
    const float* freqs  = (const float*)d_in[1];
    const float* wq_a   = (const float*)d_in[3];
    const float* qnw    = (const float*)d_in[4];
    const float* wq_b   = (const float*)d_in[5];
    const float* wkv_a  = (const float*)d_in[6];
    const float* kvnw   = (const float*)d_in[7];
    const float* wkv_b  = (const float*)d_in[8];
    const float* wo     = (const float*)d_in[9];
    float* out = (float*)d_out;
    (void)ws_size; (void)in_sizes; (void)n_in; (void)out_size;

    char* ws = (char*)d_ws;
    ushort* q_abs  = (ushort*)(ws + 0);
    ushort* q_lat  = (ushort*)(ws + 0);
    ushort* kv     = (ushort*)(ws + 12582912);
    ushort* xb     = (ushort*)(ws + 17301504);
    ushort* wq_aT  = (ushort*)(ws + 34078720);
    ushort* wq_bT  = (ushort*)(ws + 40370176);
    ushort* wkv_aT = (ushort*)(ws + 49807360);
    ushort* q      = (ushort*)(ws + 67108864);
    ushort* o2     = (ushort*)(ws + 67108864);
    ushort* qpe    = (ushort*)(ws + 92274688);
    ushort* kvc    = (ushort*)(ws + 100663296);
    ushort* kvcT   = (ushort*)(ws + 104857600);
    ushort* kpe    = (ushort*)(ws + 109051904);
    ushort* wkv_bC = (ushort*)(ws + 109576192);
    ushort* wkv_bT = (ushort*)(ws + 113770496);
    ushort* woT    = (ushort*)(ws + 117964800);

    dim3 tb(32, 8);
    transpose_f32_bf16<<<dim3(48, 64), tb, 0, stream>>>(wq_a, wq_aT, 2048, 1536);
    transpose_f32_bf16<<<dim3(96, 48), tb, 0, stream>>>(wq_b, wq_bT, 1536, 3072);
    transpose_f32_bf16<<<dim3(18, 64), tb, 0, stream>>>(wkv_a, wkv_aT, 2048, 576);
    transpose_f32_bf16<<<dim3(128, 16), tb, 0, stream>>>(wkv_b, wkv_bT, 512, 4096);
    transpose_f32_bf16<<<dim3(64, 64), tb, 0, stream>>>(wo, woT, 2048, 2048);
    cvt_f32_bf16<<<8192, 256, 0, stream>>>(x, xb, 8388608L);
    cvt_f32_bf16<<<2048, 256, 0, stream>>>(wkv_b, wkv_bC, 2097152L);

    // q_lat = x @ wq_a            (4096 x 1536, K=2048)
    gemm_bt128<<<dim3(12, 32, 1), 256, 0, stream>>>(xb, wq_aT, q_lat, 2048, 2048, 2048, 1536, 0, 0, 0, 0);
    // qn = rmsnorm(q_lat) (in place)
    rms1536<<<4096, 256, 0, stream>>>(q_lat, qnw, q_lat);
    // q = qn @ wq_b               (4096 x 3072, K=1536)
    gemm_bt128<<<dim3(24, 32, 1), 256, 0, stream>>>(q_lat, wq_bT, q, 1536, 1536, 1536, 3072, 0, 0, 0, 0);
    // q_pe = rope(q[..., 128:192])
    qrope<<<4096, 256, 0, stream>>>(q, freqs, qpe);
    // kv = x @ wkv_a              (4096 x 576, K=2048) — N=576 not /128, keep 64-tile
    gemm_bt<<<dim3(9, 64, 1), 256, 0, stream>>>(xb, wkv_aT, kv, 2048, 2048, 2048, 576, 0, 0, 0, 0);
    // kvc / kvcT / kpe
    kvprep<<<4096, 256, 0, stream>>>(kv, kvnw, freqs, kvc, kvcT, kpe);
    // q_abs[h] = q_nope[h] @ wkv_b_mat[h,:128]^T   (N=512 per head -> grid.x = 4)
    gemm_bt128<<<dim3(4, 32, 16), 256, 0, stream>>>(q, wkv_bC, q_abs, 128, 3072, 4096, 8192, 192, 256, 512, 0);
    // flash attention; O overwrites q_abs in place
    mla_attn4<<<dim3(16, 16, 2), 256, 0, stream>>>(q_abs, qpe, kvc, kvcT, kpe);
    // o2[h] = o[h] @ wkv_b_mat[h,128:]   (N=128 per head)
    gemm_bt128<<<dim3(1, 32, 16), 256, 0, stream>>>(q_abs, wkv_bT + 128L * 512, o2, 512, 8192, 512, 2048, 512, 131072, 128, 0);
    // out = o2 @ wo (fp32 output)
    gemm_bt128<<<dim3(16, 32, 1), 256, 0, stream>>>(o2, woT, out, 2048, 2048, 2048, 2048, 0, 0, 0, 1);
}